// Round 6
// baseline (160.715 us; speedup 1.0000x reference)
//
#include <hip/hip_runtime.h>
#include <stdint.h>

typedef unsigned short u16;
typedef unsigned int   u32;
typedef __bf16 bf16_t;
typedef bf16_t bf16x8 __attribute__((ext_vector_type(8)));
typedef bf16_t bf16x2 __attribute__((ext_vector_type(2)));
typedef float  f32x2  __attribute__((ext_vector_type(2)));
typedef float  f32x4  __attribute__((ext_vector_type(4)));

// bs=8, H=8 -> bH=64 ; T=1024 ; ch=64 ; classes 0..7, null token idx 8.
// Math: k-bias is row-constant over surviving keys -> drops out of softmax;
// v-bias passes through softmax as exactly +v_bias -> added in epilogue;
// counter==2 -> out = 0.5*(A_null + A_class).  No-max softmax: logits in
// exp2-domain have sigma~1.44 (scale folded into Q), so raw exp2 is safe.
// Class-stream factorization (R13): on surviving keys class(q)==class(k), so
// S_b = S_0 + per-key scalar; pb = p0 * wfk[k] under the mask, with
// wfk[k] = exp2(QSCALE*(t_{class(k)}-t_n) . K[k]) precomputed in prep.
//
// R14 (repair): R13 shed pipe work (MFMA 12.9->9.6us, VALU 19.9->17.4us) but
// dur rose 49.7->54.5us = added stalls.  (1) s_setprio removed -- our 4-wave
// barrier-locked structure is the m190-negative case, not the m191-positive
// one.  (2) per-tile seg/wtab global loads were issued after the barrier and
// consumed in softmax (~300-600cy fresh VMEM latency in the serial chain,
// 8 waves/CU can't hide it).  Now folded into per-lane masked factors
// wm = (cls(k)==cls(q)) ? wfk : 0, prefetched ONE TILE AHEAD between
// softmax-use and PV -> latency buries under PV+QK; softmax hot phase is
// just pb = p0*wm (cmp/cndmask also moved off the hot phase).
#define QSCALE 0.18033688011112042f   /* 0.125 * log2(e) */

__device__ __forceinline__ u32 pkbf(float a, float b) {
  f32x2 x = {a, b};
  bf16x2 y = __builtin_convertvector(x, bf16x2);   // RNE; v_cvt_pk_bf16_f32
  union { bf16x2 v; u32 u; } c; c.v = y; return c.u;
}

__device__ __forceinline__ float fexp2(float x) {
#if __has_builtin(__builtin_amdgcn_exp2f)
  return __builtin_amdgcn_exp2f(x);
#else
  float r;
  asm("v_exp_f32 %0, %1\n\ts_nop 0" : "=v"(r) : "v"(x));
  return r;
#endif
}

// async global->LDS, 16B per lane.  HW dest = wave-uniform base + lane*16.
__device__ __forceinline__ void gload_lds16(const void* g, void* l) {
  __builtin_amdgcn_global_load_lds(
      (const __attribute__((address_space(1))) void*)g,
      (__attribute__((address_space(3))) void*)l, 16, 0, 0);
}

// ---- kernel 0: token projections -------------------------------------------
__global__ void tok_kernel(const float* __restrict__ W, const float* __restrict__ E,
                           float* __restrict__ tok) {
  int c = blockIdx.x;           // 0..8
  int j = threadIdx.x;          // 0..191
  const f32x4* wr = (const f32x4*)(W + j * 512);
  const f32x4* er = (const f32x4*)(E + c * 512);
  float acc = 0.f;
  for (int i = 0; i < 128; ++i) {
    f32x4 w = wr[i], e = er[i];
    acc += w.x * e.x + w.y * e.y + w.z * e.z + w.w * e.w;
  }
  tok[c * 192 + j] = acc;
}

// ---- kernel 1: prep ---------------------------------------------------------
// block B = (bh,kt) -> 16KB tile image: [K 8KB | V 8KB], bf16, XOR-swizzled
// (elem ^= (row&7)<<3 within each row), plus wtab[B][64] = per-key class
// correction factors wfk.
__global__ __launch_bounds__(256)
void prep_kernel(const float* __restrict__ qkv, const int* __restrict__ seg,
                 const float* __restrict__ tok, u16* __restrict__ tiles,
                 float* __restrict__ wtab) {
  __shared__ float part[256];
  const int B = blockIdx.x;                 // 0..1023
  const int tid = threadIdx.x;
  const int bh = B >> 4, kt = B & 15;
  const int s0 = kt * 64;
  const int b  = bh >> 3;
  const float* qg = qkv + (size_t)bh * 192 * 1024;
  u16* img = tiles + (size_t)B * 8192;      // 16 KiB per (bh,kt)
  // K half: thread -> (s = tid&63, g = tid>>6), 16 d's, d-strided loads.
  {
    const int s = tid & 63, g = tid >> 6;
    const float* kb = qg + (size_t)(64 + g * 16) * 1024 + s0 + s;
    float kf[16];
#pragma unroll
    for (int i = 0; i < 16; ++i) kf[i] = kb[(size_t)i * 1024];
    u32 kp[8];
#pragma unroll
    for (int j2 = 0; j2 < 8; ++j2) kp[j2] = pkbf(kf[2 * j2], kf[2 * j2 + 1]);
    const int xr = (s & 7) << 3;
    *(uint4*)&img[s * 64 + ((g * 16)     ^ xr)] = make_uint4(kp[0], kp[1], kp[2], kp[3]);
    *(uint4*)&img[s * 64 + ((g * 16 + 8) ^ xr)] = make_uint4(kp[4], kp[5], kp[6], kp[7]);
    // wfk partial: (t_c - t_n)[d in my 16] . K[s][d]   (q-bias region [0:64])
    const int cs = seg[b * 1024 + s0 + s];
    const f32x4* tc = (const f32x4*)(tok + cs * 192 + g * 16);
    const f32x4* tn = (const f32x4*)(tok + 8 * 192 + g * 16);
    float pd = 0.f;
#pragma unroll
    for (int i = 0; i < 4; ++i) {
      f32x4 a = tc[i], n = tn[i];
      pd += (a.x - n.x) * kf[4 * i + 0] + (a.y - n.y) * kf[4 * i + 1] +
            (a.z - n.z) * kf[4 * i + 2] + (a.w - n.w) * kf[4 * i + 3];
    }
    part[s * 4 + g] = pd;
  }
  // V half: thread -> (dg = tid>>4 : 4 d's, g = tid&15 : 4 consecutive s).
  // col' base for s-group g: cp = ((g>>3)&1)*32 + (g&3)*8 + ((g>>2)&1)*4.
  {
    const int g = tid & 15, dg = tid >> 4;
    const int cp = ((g >> 3) & 1) * 32 + (g & 3) * 8 + ((g >> 2) & 1) * 4;
    const float* vb = qg + (size_t)(128 + dg * 4) * 1024 + s0 + g * 4;
#pragma unroll
    for (int i = 0; i < 4; ++i) {
      f32x4 v = *(const f32x4*)(vb + (size_t)i * 1024);
      const int d = dg * 4 + i;
      *(uint2*)&img[4096 + d * 64 + (cp ^ ((d & 7) << 3))] =
          make_uint2(pkbf(v.x, v.y), pkbf(v.z, v.w));
    }
  }
  __syncthreads();
  if (tid < 64) {
    f32x4 p4 = *(const f32x4*)&part[tid * 4];
    wtab[(size_t)B * 64 + tid] = fexp2(QSCALE * ((p4.x + p4.y) + (p4.z + p4.w)));
  }
}

// ---- kernel 2: two-qcol flash attention with factorized class stream -------
__global__ __launch_bounds__(256, 2)
void attn_kernel(const float* __restrict__ qkv, const int* __restrict__ seg,
                 const float* __restrict__ tok, const u16* __restrict__ tiles,
                 const float* __restrict__ wtab, float* __restrict__ out) {
  // tiles: [buf0 16KB | buf1 16KB] = 32768 B; epilogue fbuf 64x132 f32 =
  // 33792 B -> alloc 33792 B.
  __shared__ __align__(16) u16 smem[16896];

  const int L  = blockIdx.x;                     // 0..511
  const int bh = (L & 7) * 8 + ((L >> 3) & 7);   // same bh -> same XCD residue
  const int qb = L >> 6;                          // 0..7 (128-query block)
  const int b  = bh >> 3;
  const int tid = threadIdx.x, wave = tid >> 6, lane = tid & 63;
  const int quad = lane >> 4, l16 = lane & 15;

  const float* qg   = qkv + (size_t)bh * 192 * 1024;
  const int*   segb = seg + b * 1024;
  const u16*   tbh  = tiles + (size_t)bh * (16 * 8192);
  const float* wbh  = wtab + (size_t)bh * (16 * 64);

  // --- per-lane query info: lane owns queries tqA (col A) and tqB (col B) ---
  const int q0i = qb * 128 + wave * 32;
  const int tqA = q0i + l16, tqB = tqA + 16;
  const int mycA = segb[tqA], mycB = segb[tqB];
  int sqA[4], sqB[4];                  // classes of epilogue rows
#pragma unroll
  for (int r = 0; r < 4; ++r) {
    sqA[r] = segb[q0i + quad * 4 + r];
    sqB[r] = segb[q0i + 16 + quad * 4 + r];
  }

  // --- Q fragments, null stream only (B-layout: n=l16=query, k=d) ----------
  const float* tn = tok + 8 * 192;
  union { u32 w[4]; bf16x8 v; } qA0[2], qB0[2];
#pragma unroll
  for (int kc = 0; kc < 2; ++kc)
#pragma unroll
    for (int jj = 0; jj < 4; ++jj) {
      int d = kc * 32 + quad * 8 + jj * 2;
      float a0 = qg[(size_t)d * 1024 + tqA];
      float a1 = qg[(size_t)(d + 1) * 1024 + tqA];
      float b0 = qg[(size_t)d * 1024 + tqB];
      float b1 = qg[(size_t)(d + 1) * 1024 + tqB];
      qA0[kc].w[jj] = pkbf((a0 + tn[d]) * QSCALE, (a1 + tn[d + 1]) * QSCALE);
      qB0[kc].w[jj] = pkbf((b0 + tn[d]) * QSCALE, (b1 + tn[d + 1]) * QSCALE);
    }

  f32x4 OA0[4], OAb[4], OB0[4], OBb[4];
#pragma unroll
  for (int dt = 0; dt < 4; ++dt) {
    OA0[dt] = (f32x4){0.f, 0.f, 0.f, 0.f};  OAb[dt] = (f32x4){0.f, 0.f, 0.f, 0.f};
    OB0[dt] = (f32x4){0.f, 0.f, 0.f, 0.f};  OBb[dt] = (f32x4){0.f, 0.f, 0.f, 0.f};
  }
  float rsA0 = 0.f, rsAb = 0.f, rsB0 = 0.f, rsBb = 0.f;

  // prologue: DMA tile 0 into buf0
  {
    const char* src = (const char*)tbh + tid * 16;
    char* dst = (char*)smem + tid * 16;
#pragma unroll
    for (int i = 0; i < 4; ++i) gload_lds16(src + i * 4096, dst + i * 4096);
  }

  const int xq = (l16 & 7) << 3;   // XOR for all row&7 == l16&7 accesses

  // masked per-key class factors for the 16 key slots this lane holds:
  // wm* = (class(key)==class(query)) ? wfk[key] : 0.   Prefetched one tile
  // ahead (loads issue between softmax-use and PV of the previous tile).
  f32x4 wmA[4], wmB[4];
#define LOAD_AUX(kt_)                                                          \
  {                                                                            \
    const int sb_ = (kt_) * 64;                                                \
    _Pragma("unroll")                                                          \
    for (int n4 = 0; n4 < 4; ++n4) {                                           \
      const int4  s4 = *(const int4*)&segb[sb_ + n4 * 16 + quad * 4];          \
      const f32x4 wv = *(const f32x4*)&wbh[sb_ + n4 * 16 + quad * 4];          \
      wmA[n4][0] = (s4.x == mycA) ? wv[0] : 0.f;                               \
      wmA[n4][1] = (s4.y == mycA) ? wv[1] : 0.f;                               \
      wmA[n4][2] = (s4.z == mycA) ? wv[2] : 0.f;                               \
      wmA[n4][3] = (s4.w == mycA) ? wv[3] : 0.f;                               \
      wmB[n4][0] = (s4.x == mycB) ? wv[0] : 0.f;                               \
      wmB[n4][1] = (s4.y == mycB) ? wv[1] : 0.f;                               \
      wmB[n4][2] = (s4.z == mycB) ? wv[2] : 0.f;                               \
      wmB[n4][3] = (s4.w == mycB) ? wv[3] : 0.f;                               \
    }                                                                          \
  }
  LOAD_AUX(0)

  // ---- key-tile loop (16 x 64 keys) ----------------------------------------
#pragma unroll 2
  for (int kt = 0; kt < 16; ++kt) {
    __syncthreads();            // drains our DMA (vmcnt 0) + frees other buf
    if (kt + 1 < 16) {          // prefetch next tile across the whole compute
      const char* src = (const char*)tbh + (size_t)(kt + 1) * 16384 + tid * 16;
      char* dst = (char*)smem + ((kt + 1) & 1) * 16384 + tid * 16;
#pragma unroll
      for (int i = 0; i < 4; ++i) gload_lds16(src + i * 4096, dst + i * 4096);
    }

    const u16* ktr = smem + (kt & 1) * 8192;   // K image [s][64]
    const u16* vls = ktr + 4096;               // V image [d][64]

    // ---- S^T = K Q^T, null stream only, two q-cols; K-frag read ONCE ------
    f32x4 SA[4], SB[4];
#pragma unroll
    for (int n4 = 0; n4 < 4; ++n4) {
      const int srow = n4 * 16 + l16;          // srow&7 == l16&7 -> xq
      f32x4 a0 = {0.f, 0.f, 0.f, 0.f}, c0 = {0.f, 0.f, 0.f, 0.f};
#pragma unroll
      for (int kc = 0; kc < 2; ++kc) {
        bf16x8 kfr = *(const bf16x8*)&ktr[srow * 64 + ((kc * 32 + quad * 8) ^ xq)];
        a0 = __builtin_amdgcn_mfma_f32_16x16x32_bf16(kfr, qA0[kc].v, a0, 0, 0, 0);
        c0 = __builtin_amdgcn_mfma_f32_16x16x32_bf16(kfr, qB0[kc].v, c0, 0, 0, 0);
      }
      SA[n4] = a0; SB[n4] = c0;
    }

    // ---- softmax: p0 = exp2(S); pb = p0 * wm ------------------------------
    union { u32 w[4]; bf16x8 v; } paA0[2], paAb[2], paB0[2], paBb[2];
#define SOFTMAX_PACK(S, wm, rs0, rsb, pa0, pab)                                \
    {                                                                          \
      float p0[4][4], pb[4][4];                                                \
      _Pragma("unroll")                                                        \
      for (int n4 = 0; n4 < 4; ++n4)                                           \
        _Pragma("unroll")                                                      \
        for (int r = 0; r < 4; ++r) {                                          \
          p0[n4][r] = fexp2(S[n4][r]);                                         \
          pb[n4][r] = p0[n4][r] * wm[n4][r];                                   \
        }                                                                      \
      _Pragma("unroll")                                                        \
      for (int n4 = 0; n4 < 4; ++n4) {                                         \
        rs0 += (p0[n4][0] + p0[n4][1]) + (p0[n4][2] + p0[n4][3]);              \
        rsb += (pb[n4][0] + pb[n4][1]) + (pb[n4][2] + pb[n4][3]);              \
      }                                                                        \
      _Pragma("unroll")                                                        \
      for (int kc = 0; kc < 2; ++kc) {                                         \
        pa0[kc].w[0] = pkbf(p0[2 * kc][0],     p0[2 * kc][1]);                 \
        pa0[kc].w[1] = pkbf(p0[2 * kc][2],     p0[2 * kc][3]);                 \
        pa0[kc].w[2] = pkbf(p0[2 * kc + 1][0], p0[2 * kc + 1][1]);             \
        pa0[kc].w[3] = pkbf(p0[2 * kc + 1][2], p0[2 * kc + 1][3]);             \
        pab[kc].w[0] = pkbf(pb[2 * kc][0],     pb[2 * kc][1]);                 \
        pab[kc].w[1] = pkbf(pb[2 * kc][2],     pb[2 * kc][3]);                 \
        pab[kc].w[2] = pkbf(pb[2 * kc + 1][0], pb[2 * kc + 1][1]);             \
        pab[kc].w[3] = pkbf(pb[2 * kc + 1][2], pb[2 * kc + 1][3]);             \
      }                                                                        \
    }
    SOFTMAX_PACK(SA, wmA, rsA0, rsAb, paA0, paAb)
    SOFTMAX_PACK(SB, wmB, rsB0, rsBb, paB0, paBb)
#undef SOFTMAX_PACK

    // wm consumed -> prefetch next tile's aux; latency hides under PV.
    if (kt + 1 < 16) LOAD_AUX(kt + 1)

    // ---- O += P V ; V-frag read ONCE feeds 4 MFMAs ------------------------
#pragma unroll
    for (int kc = 0; kc < 2; ++kc) {
      const int co = (kc * 32 + quad * 8) ^ xq;
#pragma unroll
      for (int dt = 0; dt < 4; ++dt) {
        bf16x8 vfr = *(const bf16x8*)&vls[(dt * 16 + l16) * 64 + co];
        OA0[dt] = __builtin_amdgcn_mfma_f32_16x16x32_bf16(paA0[kc].v, vfr, OA0[dt], 0, 0, 0);
        OAb[dt] = __builtin_amdgcn_mfma_f32_16x16x32_bf16(paAb[kc].v, vfr, OAb[dt], 0, 0, 0);
        OB0[dt] = __builtin_amdgcn_mfma_f32_16x16x32_bf16(paB0[kc].v, vfr, OB0[dt], 0, 0, 0);
        OBb[dt] = __builtin_amdgcn_mfma_f32_16x16x32_bf16(paBb[kc].v, vfr, OBb[dt], 0, 0, 0);
      }
    }
  }
#undef LOAD_AUX

  // ---- denominators: reduce across quads, then broadcast rows --------------
  rsA0 += __shfl_xor(rsA0, 16, 64);  rsA0 += __shfl_xor(rsA0, 32, 64);
  rsAb += __shfl_xor(rsAb, 16, 64);  rsAb += __shfl_xor(rsAb, 32, 64);
  rsB0 += __shfl_xor(rsB0, 16, 64);  rsB0 += __shfl_xor(rsB0, 32, 64);
  rsBb += __shfl_xor(rsBb, 16, 64);  rsBb += __shfl_xor(rsBb, 32, 64);
  float invA0[4], invAb[4], invB0[4], invBb[4];
#pragma unroll
  for (int r = 0; r < 4; ++r) {
    float a0 = __shfl(rsA0, quad * 4 + r, 16);
    float ab = __shfl(rsAb, quad * 4 + r, 16);
    float b0 = __shfl(rsB0, quad * 4 + r, 16);
    float bb = __shfl(rsBb, quad * 4 + r, 16);
    invA0[r] = (a0 > 0.f) ? 1.f / a0 : 0.f;
    invAb[r] = (ab > 0.f) ? 1.f / ab : 0.f;
    invB0[r] = (b0 > 0.f) ? 1.f / b0 : 0.f;
    invBb[r] = (bb > 0.f) ? 1.f / bb : 0.f;
  }

  // ---- epilogue: divide, add analytic v-biases, transpose via LDS, store ---
  __syncthreads();                        // all LDS tile reads done
  float* fbuf = (float*)smem;             // [64 d][132] fp32 (33792 B)
  const float* tvn = tok + 8 * 192 + 128;
#pragma unroll
  for (int dt = 0; dt < 4; ++dt) {
    const int d = dt * 16 + l16;
    const float bn = tvn[d];
    f32x4 wA, wB;
#pragma unroll
    for (int r = 0; r < 4; ++r) {
      float bcA = tok[sqA[r] * 192 + 128 + d];
      float bcB = tok[sqB[r] * 192 + 128 + d];
      wA[r] = 0.5f * (OA0[dt][r] * invA0[r] + bn + OAb[dt][r] * invAb[r] + bcA);
      wB[r] = 0.5f * (OB0[dt][r] * invB0[r] + bn + OBb[dt][r] * invBb[r] + bcB);
    }
    *(f32x4*)&fbuf[d * 132 + wave * 32 + quad * 4]      = wA;
    *(f32x4*)&fbuf[d * 132 + wave * 32 + 16 + quad * 4] = wB;
  }
  __syncthreads();
  {
    // out flat = d*65536 + bh*1024 + t   (stacked (ch, bH, T) row-major)
    const size_t obase = (size_t)bh * 1024 + qb * 128;
    for (int i = tid; i < 8192; i += 256) {
      int d = i >> 7, t = i & 127;
      out[(size_t)d * 65536 + obase + t] = fbuf[d * 132 + t];
    }
  }
}

// ---- host ------------------------------------------------------------------
extern "C" void kernel_launch(void* const* d_in, const int* in_sizes, int n_in,
                              void* d_out, int out_size, void* d_ws, size_t ws_size,
                              hipStream_t stream) {
  (void)in_sizes; (void)n_in; (void)out_size; (void)ws_size;
  const float* qkv   = (const float*)d_in[0];
  const int*   amask = (const int*)d_in[1];
  const float* emb   = (const float*)d_in[2];
  const float* wcls  = (const float*)d_in[3];
  float* tok   = (float*)d_ws;                       // 1728 floats
  u16*   tiles = (u16*)((char*)d_ws + 8192);         // 16 MiB of tile images
  float* wtab  = (float*)((char*)d_ws + 8192 + 16 * 1024 * 1024);  // 256 KiB
  float* out = (float*)d_out;

  hipLaunchKernelGGL(tok_kernel, dim3(9), dim3(192), 0, stream, wcls, emb, tok);
  hipLaunchKernelGGL(prep_kernel, dim3(1024), dim3(256), 0, stream,
                     qkv, amask, tok, tiles, wtab);
  hipLaunchKernelGGL(attn_kernel, dim3(512), dim3(256), 0, stream,
                     qkv, amask, tok, tiles, wtab, out);
}

// Round 8
// 145.298 us; speedup vs baseline: 1.1061x; 1.1061x over previous
//
#include <hip/hip_runtime.h>
#include <stdint.h>

typedef unsigned short u16;
typedef unsigned int   u32;
typedef __bf16 bf16_t;
typedef bf16_t bf16x8 __attribute__((ext_vector_type(8)));
typedef bf16_t bf16x2 __attribute__((ext_vector_type(2)));
typedef float  f32x2  __attribute__((ext_vector_type(2)));
typedef float  f32x4  __attribute__((ext_vector_type(4)));

// bs=8, H=8 -> bH=64 ; T=1024 ; ch=64 ; classes 0..7, null token idx 8.
// Math: k-bias is row-constant over surviving keys -> drops out of softmax;
// v-bias passes through softmax as exactly +v_bias -> added in epilogue;
// counter==2 -> out = 0.5*(A_null + A_class).  No-max softmax: logits in
// exp2-domain have sigma~1.44 (scale folded into Q), so raw exp2 is safe.
// Class-stream factorization: on surviving keys class(q)==class(k), so
// S_b = S_0 + per-key scalar; pb = p0 * wfk[k] under the mask, with
// wfk[k] = exp2(QSCALE*(t_{class(k)}-t_n) . K[k]) precomputed in prep.
//
// R16 = R15 with the dropped rsBb shfl_xor reduction restored (R15's absmax
// 4.22 was that one missing line, not the math).  R15 theory under test:
// WRITE_SIZE R12=16.8MB clean / R13=+6.7 / R14=+34MB were scratch spills;
// allocator caps at 128 VGPR.  R14's cause: wm persistent across PV+barrier.
// R13's suspected cause: s_setprio pinning live ranges.  Here: NO setprio,
// wm TRANSIENT per tile (loads at loop top, covered by QK MFMA latency,
// dead after softmax).  Verification signal: WRITE_SIZE ~16.4MB.
#define QSCALE 0.18033688011112042f   /* 0.125 * log2(e) */

__device__ __forceinline__ u32 pkbf(float a, float b) {
  f32x2 x = {a, b};
  bf16x2 y = __builtin_convertvector(x, bf16x2);   // RNE; v_cvt_pk_bf16_f32
  union { bf16x2 v; u32 u; } c; c.v = y; return c.u;
}

__device__ __forceinline__ float fexp2(float x) {
#if __has_builtin(__builtin_amdgcn_exp2f)
  return __builtin_amdgcn_exp2f(x);
#else
  float r;
  asm("v_exp_f32 %0, %1\n\ts_nop 0" : "=v"(r) : "v"(x));
  return r;
#endif
}

// async global->LDS, 16B per lane.  HW dest = wave-uniform base + lane*16.
__device__ __forceinline__ void gload_lds16(const void* g, void* l) {
  __builtin_amdgcn_global_load_lds(
      (const __attribute__((address_space(1))) void*)g,
      (__attribute__((address_space(3))) void*)l, 16, 0, 0);
}

// ---- kernel 0: token projections -------------------------------------------
__global__ void tok_kernel(const float* __restrict__ W, const float* __restrict__ E,
                           float* __restrict__ tok) {
  int c = blockIdx.x;           // 0..8
  int j = threadIdx.x;          // 0..191
  const f32x4* wr = (const f32x4*)(W + j * 512);
  const f32x4* er = (const f32x4*)(E + c * 512);
  float acc = 0.f;
  for (int i = 0; i < 128; ++i) {
    f32x4 w = wr[i], e = er[i];
    acc += w.x * e.x + w.y * e.y + w.z * e.z + w.w * e.w;
  }
  tok[c * 192 + j] = acc;
}

// ---- kernel 1: prep ---------------------------------------------------------
// block B = (bh,kt) -> 16KB tile image: [K 8KB | V 8KB], bf16, XOR-swizzled
// (elem ^= (row&7)<<3 within each row), plus wtab[B][64] = per-key class
// correction factors wfk.
__global__ __launch_bounds__(256)
void prep_kernel(const float* __restrict__ qkv, const int* __restrict__ seg,
                 const float* __restrict__ tok, u16* __restrict__ tiles,
                 float* __restrict__ wtab) {
  __shared__ float part[256];
  const int B = blockIdx.x;                 // 0..1023
  const int tid = threadIdx.x;
  const int bh = B >> 4, kt = B & 15;
  const int s0 = kt * 64;
  const int b  = bh >> 3;
  const float* qg = qkv + (size_t)bh * 192 * 1024;
  u16* img = tiles + (size_t)B * 8192;      // 16 KiB per (bh,kt)
  // K half: thread -> (s = tid&63, g = tid>>6), 16 d's, d-strided loads.
  {
    const int s = tid & 63, g = tid >> 6;
    const float* kb = qg + (size_t)(64 + g * 16) * 1024 + s0 + s;
    float kf[16];
#pragma unroll
    for (int i = 0; i < 16; ++i) kf[i] = kb[(size_t)i * 1024];
    u32 kp[8];
#pragma unroll
    for (int j2 = 0; j2 < 8; ++j2) kp[j2] = pkbf(kf[2 * j2], kf[2 * j2 + 1]);
    const int xr = (s & 7) << 3;
    *(uint4*)&img[s * 64 + ((g * 16)     ^ xr)] = make_uint4(kp[0], kp[1], kp[2], kp[3]);
    *(uint4*)&img[s * 64 + ((g * 16 + 8) ^ xr)] = make_uint4(kp[4], kp[5], kp[6], kp[7]);
    // wfk partial: (t_c - t_n)[d in my 16] . K[s][d]   (q-bias region [0:64])
    const int cs = seg[b * 1024 + s0 + s];
    const f32x4* tc = (const f32x4*)(tok + cs * 192 + g * 16);
    const f32x4* tn = (const f32x4*)(tok + 8 * 192 + g * 16);
    float pd = 0.f;
#pragma unroll
    for (int i = 0; i < 4; ++i) {
      f32x4 a = tc[i], n = tn[i];
      pd += (a.x - n.x) * kf[4 * i + 0] + (a.y - n.y) * kf[4 * i + 1] +
            (a.z - n.z) * kf[4 * i + 2] + (a.w - n.w) * kf[4 * i + 3];
    }
    part[s * 4 + g] = pd;
  }
  // V half: thread -> (dg = tid>>4 : 4 d's, g = tid&15 : 4 consecutive s).
  // col' base for s-group g: cp = ((g>>3)&1)*32 + (g&3)*8 + ((g>>2)&1)*4.
  {
    const int g = tid & 15, dg = tid >> 4;
    const int cp = ((g >> 3) & 1) * 32 + (g & 3) * 8 + ((g >> 2) & 1) * 4;
    const float* vb = qg + (size_t)(128 + dg * 4) * 1024 + s0 + g * 4;
#pragma unroll
    for (int i = 0; i < 4; ++i) {
      f32x4 v = *(const f32x4*)(vb + (size_t)i * 1024);
      const int d = dg * 4 + i;
      *(uint2*)&img[4096 + d * 64 + (cp ^ ((d & 7) << 3))] =
          make_uint2(pkbf(v.x, v.y), pkbf(v.z, v.w));
    }
  }
  __syncthreads();
  if (tid < 64) {
    f32x4 p4 = *(const f32x4*)&part[tid * 4];
    wtab[(size_t)B * 64 + tid] = fexp2(QSCALE * ((p4.x + p4.y) + (p4.z + p4.w)));
  }
}

// ---- kernel 2: two-qcol flash attention with factorized class stream -------
__global__ __launch_bounds__(256, 2)
void attn_kernel(const float* __restrict__ qkv, const int* __restrict__ seg,
                 const float* __restrict__ tok, const u16* __restrict__ tiles,
                 const float* __restrict__ wtab, float* __restrict__ out) {
  // tiles: [buf0 16KB | buf1 16KB] = 32768 B; epilogue fbuf 64x132 f32 =
  // 33792 B -> alloc 33792 B.
  __shared__ __align__(16) u16 smem[16896];

  const int L  = blockIdx.x;                     // 0..511
  const int bh = (L & 7) * 8 + ((L >> 3) & 7);   // same bh -> same XCD residue
  const int qb = L >> 6;                          // 0..7 (128-query block)
  const int b  = bh >> 3;
  const int tid = threadIdx.x, wave = tid >> 6, lane = tid & 63;
  const int quad = lane >> 4, l16 = lane & 15;

  const float* qg   = qkv + (size_t)bh * 192 * 1024;
  const int*   segb = seg + b * 1024;
  const u16*   tbh  = tiles + (size_t)bh * (16 * 8192);
  const float* wbh  = wtab + (size_t)bh * (16 * 64);

  // --- per-lane query info: lane owns queries tqA (col A) and tqB (col B) ---
  const int q0i = qb * 128 + wave * 32;
  const int tqA = q0i + l16, tqB = tqA + 16;
  const int mycA = segb[tqA], mycB = segb[tqB];
  int sqA[4], sqB[4];                  // classes of epilogue rows
#pragma unroll
  for (int r = 0; r < 4; ++r) {
    sqA[r] = segb[q0i + quad * 4 + r];
    sqB[r] = segb[q0i + 16 + quad * 4 + r];
  }

  // --- Q fragments, null stream only (B-layout: n=l16=query, k=d) ----------
  const float* tn = tok + 8 * 192;
  union { u32 w[4]; bf16x8 v; } qA0[2], qB0[2];
#pragma unroll
  for (int kc = 0; kc < 2; ++kc)
#pragma unroll
    for (int jj = 0; jj < 4; ++jj) {
      int d = kc * 32 + quad * 8 + jj * 2;
      float a0 = qg[(size_t)d * 1024 + tqA];
      float a1 = qg[(size_t)(d + 1) * 1024 + tqA];
      float b0 = qg[(size_t)d * 1024 + tqB];
      float b1 = qg[(size_t)(d + 1) * 1024 + tqB];
      qA0[kc].w[jj] = pkbf((a0 + tn[d]) * QSCALE, (a1 + tn[d + 1]) * QSCALE);
      qB0[kc].w[jj] = pkbf((b0 + tn[d]) * QSCALE, (b1 + tn[d + 1]) * QSCALE);
    }

  f32x4 OA0[4], OAb[4], OB0[4], OBb[4];
#pragma unroll
  for (int dt = 0; dt < 4; ++dt) {
    OA0[dt] = (f32x4){0.f, 0.f, 0.f, 0.f};  OAb[dt] = (f32x4){0.f, 0.f, 0.f, 0.f};
    OB0[dt] = (f32x4){0.f, 0.f, 0.f, 0.f};  OBb[dt] = (f32x4){0.f, 0.f, 0.f, 0.f};
  }
  float rsA0 = 0.f, rsAb = 0.f, rsB0 = 0.f, rsBb = 0.f;

  // prologue: DMA tile 0 into buf0
  {
    const char* src = (const char*)tbh + tid * 16;
    char* dst = (char*)smem + tid * 16;
#pragma unroll
    for (int i = 0; i < 4; ++i) gload_lds16(src + i * 4096, dst + i * 4096);
  }

  const int xq = (l16 & 7) << 3;   // XOR for all row&7 == l16&7 accesses

  // ---- key-tile loop (16 x 64 keys) ----------------------------------------
#pragma unroll 2
  for (int kt = 0; kt < 16; ++kt) {
    const int s0 = kt * 64;
    __syncthreads();            // drains our DMA (vmcnt 0) + frees other buf
    if (kt + 1 < 16) {          // prefetch next tile across the whole compute
      const char* src = (const char*)tbh + (size_t)(kt + 1) * 16384 + tid * 16;
      char* dst = (char*)smem + ((kt + 1) & 1) * 16384 + tid * 16;
#pragma unroll
      for (int i = 0; i < 4; ++i) gload_lds16(src + i * 4096, dst + i * 4096);
    }
    // masked per-key class factors, TRANSIENT (dead after softmax).  Loads
    // issue here; ~300cy L2 latency covered by the QK MFMA cluster below.
    f32x4 wmA[4], wmB[4];
#pragma unroll
    for (int n4 = 0; n4 < 4; ++n4) {
      const int4  s4 = *(const int4*)&segb[s0 + n4 * 16 + quad * 4];
      const f32x4 wv = *(const f32x4*)&wbh[s0 + n4 * 16 + quad * 4];
      wmA[n4][0] = (s4.x == mycA) ? wv[0] : 0.f;
      wmA[n4][1] = (s4.y == mycA) ? wv[1] : 0.f;
      wmA[n4][2] = (s4.z == mycA) ? wv[2] : 0.f;
      wmA[n4][3] = (s4.w == mycA) ? wv[3] : 0.f;
      wmB[n4][0] = (s4.x == mycB) ? wv[0] : 0.f;
      wmB[n4][1] = (s4.y == mycB) ? wv[1] : 0.f;
      wmB[n4][2] = (s4.z == mycB) ? wv[2] : 0.f;
      wmB[n4][3] = (s4.w == mycB) ? wv[3] : 0.f;
    }

    const u16* ktr = smem + (kt & 1) * 8192;   // K image [s][64]
    const u16* vls = ktr + 4096;               // V image [d][64]

    // ---- S^T = K Q^T, null stream only, two q-cols; K-frag read ONCE ------
    f32x4 SA[4], SB[4];
#pragma unroll
    for (int n4 = 0; n4 < 4; ++n4) {
      const int srow = n4 * 16 + l16;          // srow&7 == l16&7 -> xq
      f32x4 a0 = {0.f, 0.f, 0.f, 0.f}, c0 = {0.f, 0.f, 0.f, 0.f};
#pragma unroll
      for (int kc = 0; kc < 2; ++kc) {
        bf16x8 kfr = *(const bf16x8*)&ktr[srow * 64 + ((kc * 32 + quad * 8) ^ xq)];
        a0 = __builtin_amdgcn_mfma_f32_16x16x32_bf16(kfr, qA0[kc].v, a0, 0, 0, 0);
        c0 = __builtin_amdgcn_mfma_f32_16x16x32_bf16(kfr, qB0[kc].v, c0, 0, 0, 0);
      }
      SA[n4] = a0; SB[n4] = c0;
    }

    // ---- softmax: p0 = exp2(S); pb = p0 * wm ------------------------------
    union { u32 w[4]; bf16x8 v; } paA0[2], paAb[2], paB0[2], paBb[2];
#define SOFTMAX_PACK(S, wm, rs0, rsb, pa0, pab)                                \
    {                                                                          \
      float p0[4][4], pb[4][4];                                                \
      _Pragma("unroll")                                                        \
      for (int n4 = 0; n4 < 4; ++n4)                                           \
        _Pragma("unroll")                                                      \
        for (int r = 0; r < 4; ++r) {                                          \
          p0[n4][r] = fexp2(S[n4][r]);                                         \
          pb[n4][r] = p0[n4][r] * wm[n4][r];                                   \
        }                                                                      \
      _Pragma("unroll")                                                        \
      for (int n4 = 0; n4 < 4; ++n4) {                                         \
        rs0 += (p0[n4][0] + p0[n4][1]) + (p0[n4][2] + p0[n4][3]);              \
        rsb += (pb[n4][0] + pb[n4][1]) + (pb[n4][2] + pb[n4][3]);              \
      }                                                                        \
      _Pragma("unroll")                                                        \
      for (int kc = 0; kc < 2; ++kc) {                                         \
        pa0[kc].w[0] = pkbf(p0[2 * kc][0],     p0[2 * kc][1]);                 \
        pa0[kc].w[1] = pkbf(p0[2 * kc][2],     p0[2 * kc][3]);                 \
        pa0[kc].w[2] = pkbf(p0[2 * kc + 1][0], p0[2 * kc + 1][1]);             \
        pa0[kc].w[3] = pkbf(p0[2 * kc + 1][2], p0[2 * kc + 1][3]);             \
        pab[kc].w[0] = pkbf(pb[2 * kc][0],     pb[2 * kc][1]);                 \
        pab[kc].w[1] = pkbf(pb[2 * kc][2],     pb[2 * kc][3]);                 \
        pab[kc].w[2] = pkbf(pb[2 * kc + 1][0], pb[2 * kc + 1][1]);             \
        pab[kc].w[3] = pkbf(pb[2 * kc + 1][2], pb[2 * kc + 1][3]);             \
      }                                                                        \
    }
    SOFTMAX_PACK(SA, wmA, rsA0, rsAb, paA0, paAb)
    SOFTMAX_PACK(SB, wmB, rsB0, rsBb, paB0, paBb)
#undef SOFTMAX_PACK

    // ---- O += P V ; V-frag read ONCE feeds 4 MFMAs ------------------------
#pragma unroll
    for (int kc = 0; kc < 2; ++kc) {
      const int co = (kc * 32 + quad * 8) ^ xq;
#pragma unroll
      for (int dt = 0; dt < 4; ++dt) {
        bf16x8 vfr = *(const bf16x8*)&vls[(dt * 16 + l16) * 64 + co];
        OA0[dt] = __builtin_amdgcn_mfma_f32_16x16x32_bf16(paA0[kc].v, vfr, OA0[dt], 0, 0, 0);
        OAb[dt] = __builtin_amdgcn_mfma_f32_16x16x32_bf16(paAb[kc].v, vfr, OAb[dt], 0, 0, 0);
        OB0[dt] = __builtin_amdgcn_mfma_f32_16x16x32_bf16(paB0[kc].v, vfr, OB0[dt], 0, 0, 0);
        OBb[dt] = __builtin_amdgcn_mfma_f32_16x16x32_bf16(paBb[kc].v, vfr, OBb[dt], 0, 0, 0);
      }
    }
  }

  // ---- denominators: reduce across quads, then broadcast rows --------------
  rsA0 += __shfl_xor(rsA0, 16, 64);  rsA0 += __shfl_xor(rsA0, 32, 64);
  rsAb += __shfl_xor(rsAb, 16, 64);  rsAb += __shfl_xor(rsAb, 32, 64);
  rsB0 += __shfl_xor(rsB0, 16, 64);  rsB0 += __shfl_xor(rsB0, 32, 64);
  rsBb += __shfl_xor(rsBb, 16, 64);  rsBb += __shfl_xor(rsBb, 32, 64);
  float invA0[4], invAb[4], invB0[4], invBb[4];
#pragma unroll
  for (int r = 0; r < 4; ++r) {
    float a0 = __shfl(rsA0, quad * 4 + r, 16);
    float ab = __shfl(rsAb, quad * 4 + r, 16);
    float b0 = __shfl(rsB0, quad * 4 + r, 16);
    float bb = __shfl(rsBb, quad * 4 + r, 16);
    invA0[r] = (a0 > 0.f) ? 1.f / a0 : 0.f;
    invAb[r] = (ab > 0.f) ? 1.f / ab : 0.f;
    invB0[r] = (b0 > 0.f) ? 1.f / b0 : 0.f;
    invBb[r] = (bb > 0.f) ? 1.f / bb : 0.f;
  }

  // ---- epilogue: divide, add analytic v-biases, transpose via LDS, store ---
  __syncthreads();                        // all LDS tile reads done
  float* fbuf = (float*)smem;             // [64 d][132] fp32 (33792 B)
  const float* tvn = tok + 8 * 192 + 128;
#pragma unroll
  for (int dt = 0; dt < 4; ++dt) {
    const int d = dt * 16 + l16;
    const float bn = tvn[d];
    f32x4 wA, wB;
#pragma unroll
    for (int r = 0; r < 4; ++r) {
      float bcA = tok[sqA[r] * 192 + 128 + d];
      float bcB = tok[sqB[r] * 192 + 128 + d];
      wA[r] = 0.5f * (OA0[dt][r] * invA0[r] + bn + OAb[dt][r] * invAb[r] + bcA);
      wB[r] = 0.5f * (OB0[dt][r] * invB0[r] + bn + OBb[dt][r] * invBb[r] + bcB);
    }
    *(f32x4*)&fbuf[d * 132 + wave * 32 + quad * 4]      = wA;
    *(f32x4*)&fbuf[d * 132 + wave * 32 + 16 + quad * 4] = wB;
  }
  __syncthreads();
  {
    // out flat = d*65536 + bh*1024 + t   (stacked (ch, bH, T) row-major)
    const size_t obase = (size_t)bh * 1024 + qb * 128;
    for (int i = tid; i < 8192; i += 256) {
      int d = i >> 7, t = i & 127;
      out[(size_t)d * 65536 + obase + t] = fbuf[d * 132 + t];
    }
  }
}

// ---- host ------------------------------------------------------------------
extern "C" void kernel_launch(void* const* d_in, const int* in_sizes, int n_in,
                              void* d_out, int out_size, void* d_ws, size_t ws_size,
                              hipStream_t stream) {
  (void)in_sizes; (void)n_in; (void)out_size; (void)ws_size;
  const float* qkv   = (const float*)d_in[0];
  const int*   amask = (const int*)d_in[1];
  const float* emb   = (const float*)d_in[2];
  const float* wcls  = (const float*)d_in[3];
  float* tok   = (float*)d_ws;                       // 1728 floats
  u16*   tiles = (u16*)((char*)d_ws + 8192);         // 16 MiB of tile images
  float* wtab  = (float*)((char*)d_ws + 8192 + 16 * 1024 * 1024);  // 256 KiB
  float* out = (float*)d_out;

  hipLaunchKernelGGL(tok_kernel, dim3(9), dim3(192), 0, stream, wcls, emb, tok);
  hipLaunchKernelGGL(prep_kernel, dim3(1024), dim3(256), 0, stream,
                     qkv, amask, tok, tiles, wtab);
  hipLaunchKernelGGL(attn_kernel, dim3(512), dim3(256), 0, stream,
                     qkv, amask, tok, tiles, wtab, out);
}

// Round 9
// 139.349 us; speedup vs baseline: 1.1533x; 1.0427x over previous
//
#include <hip/hip_runtime.h>
#include <stdint.h>

typedef unsigned short u16;
typedef unsigned int   u32;
typedef __bf16 bf16_t;
typedef bf16_t bf16x8 __attribute__((ext_vector_type(8)));
typedef bf16_t bf16x2 __attribute__((ext_vector_type(2)));
typedef float  f32x2  __attribute__((ext_vector_type(2)));
typedef float  f32x4  __attribute__((ext_vector_type(4)));

// bs=8, H=8 -> bH=64 ; T=1024 ; ch=64 ; classes 0..7, null token idx 8.
// Math: k-bias is row-constant over surviving keys -> drops out of softmax;
// v-bias passes through softmax as exactly +v_bias -> added in epilogue;
// counter==2 -> out = 0.5*(A_null + A_class).  No-max softmax: logits in
// exp2-domain have sigma~1.44 (scale folded into Q), so raw exp2 is safe.
// Class-stream factorization (verified R16): on surviving keys
// class(q)==class(k), so pb = p0 * wfk[k] under the mask, with
// wfk[k] = exp2(QSCALE*(t_{class(k)}-t_n) . K[k]) precomputed in prep.
//
// R17: occupancy round.  R16 counters: attn 46.5us, Occ 16.8% -- grid 512 =
// 2 blocks/CU = 2 waves/SIMD is the binding constraint (not VGPR/LDS), and
// the kernel is latency-bound (Mfma 21 + VALU 39, both low).  (1) attn back
// to 64q/4-wave/1-qcol blocks (grid 1024): 4 blocks/CU x 4 waves = 4
// waves/SIMD, 2x latency hiding; per-query MFMA/exp2 unchanged by the
// split; LDS reads/query double (pipe was only ~26% busy); tile re-reads
// stay L2-resident (2MB/XCD).  (2) tok_kernel was the hidden +10us: 9
// blocks x 128-iter latency-bound loops on 9 CUs.  Now 432 blocks x 4
// waves, one (c,j) output per wave via shfl reduce (~2us).  prep unchanged.
// Spill tripwire: WRITE_SIZE must stay ~16.4MB.
#define QSCALE 0.18033688011112042f   /* 0.125 * log2(e) */

__device__ __forceinline__ u32 pkbf(float a, float b) {
  f32x2 x = {a, b};
  bf16x2 y = __builtin_convertvector(x, bf16x2);   // RNE; v_cvt_pk_bf16_f32
  union { bf16x2 v; u32 u; } c; c.v = y; return c.u;
}

__device__ __forceinline__ float fexp2(float x) {
#if __has_builtin(__builtin_amdgcn_exp2f)
  return __builtin_amdgcn_exp2f(x);
#else
  float r;
  asm("v_exp_f32 %0, %1\n\ts_nop 0" : "=v"(r) : "v"(x));
  return r;
#endif
}

// async global->LDS, 16B per lane.  HW dest = wave-uniform base + lane*16.
__device__ __forceinline__ void gload_lds16(const void* g, void* l) {
  __builtin_amdgcn_global_load_lds(
      (const __attribute__((address_space(1))) void*)g,
      (__attribute__((address_space(3))) void*)l, 16, 0, 0);
}

// ---- kernel 0: token projections (wave-parallel) ---------------------------
// 432 blocks x 4 waves; each wave computes one tok[c][j] = W[j,:].E[c,:]
// (1728 outputs).  Lane covers 8 elems; shfl_xor reduce; lane 0 stores.
__global__ __launch_bounds__(256)
void tok_kernel(const float* __restrict__ W, const float* __restrict__ E,
                float* __restrict__ tok) {
  const int gw = blockIdx.x * 4 + (threadIdx.x >> 6);   // 0..1727
  const int lane = threadIdx.x & 63;
  const int c = gw / 192, j = gw - c * 192;
  const f32x4* w4 = (const f32x4*)(W + (size_t)j * 512) + lane * 2;
  const f32x4* e4 = (const f32x4*)(E + (size_t)c * 512) + lane * 2;
  float acc = 0.f;
#pragma unroll
  for (int i = 0; i < 2; ++i) {
    f32x4 w = w4[i], e = e4[i];
    acc += w.x * e.x + w.y * e.y + w.z * e.z + w.w * e.w;
  }
#pragma unroll
  for (int off = 32; off; off >>= 1) acc += __shfl_xor(acc, off, 64);
  if (lane == 0) tok[c * 192 + j] = acc;
}

// ---- kernel 1: prep (unchanged from R16, verified) --------------------------
// block B = (bh,kt) -> 16KB tile image: [K 8KB | V 8KB], bf16, XOR-swizzled
// (elem ^= (row&7)<<3 within each row), plus wtab[B][64] = per-key class
// correction factors wfk.
__global__ __launch_bounds__(256)
void prep_kernel(const float* __restrict__ qkv, const int* __restrict__ seg,
                 const float* __restrict__ tok, u16* __restrict__ tiles,
                 float* __restrict__ wtab) {
  __shared__ float part[256];
  const int B = blockIdx.x;                 // 0..1023
  const int tid = threadIdx.x;
  const int bh = B >> 4, kt = B & 15;
  const int s0 = kt * 64;
  const int b  = bh >> 3;
  const float* qg = qkv + (size_t)bh * 192 * 1024;
  u16* img = tiles + (size_t)B * 8192;      // 16 KiB per (bh,kt)
  // K half: thread -> (s = tid&63, g = tid>>6), 16 d's, d-strided loads.
  {
    const int s = tid & 63, g = tid >> 6;
    const float* kb = qg + (size_t)(64 + g * 16) * 1024 + s0 + s;
    float kf[16];
#pragma unroll
    for (int i = 0; i < 16; ++i) kf[i] = kb[(size_t)i * 1024];
    u32 kp[8];
#pragma unroll
    for (int j2 = 0; j2 < 8; ++j2) kp[j2] = pkbf(kf[2 * j2], kf[2 * j2 + 1]);
    const int xr = (s & 7) << 3;
    *(uint4*)&img[s * 64 + ((g * 16)     ^ xr)] = make_uint4(kp[0], kp[1], kp[2], kp[3]);
    *(uint4*)&img[s * 64 + ((g * 16 + 8) ^ xr)] = make_uint4(kp[4], kp[5], kp[6], kp[7]);
    // wfk partial: (t_c - t_n)[d in my 16] . K[s][d]   (q-bias region [0:64])
    const int cs = seg[b * 1024 + s0 + s];
    const f32x4* tc = (const f32x4*)(tok + cs * 192 + g * 16);
    const f32x4* tn = (const f32x4*)(tok + 8 * 192 + g * 16);
    float pd = 0.f;
#pragma unroll
    for (int i = 0; i < 4; ++i) {
      f32x4 a = tc[i], n = tn[i];
      pd += (a.x - n.x) * kf[4 * i + 0] + (a.y - n.y) * kf[4 * i + 1] +
            (a.z - n.z) * kf[4 * i + 2] + (a.w - n.w) * kf[4 * i + 3];
    }
    part[s * 4 + g] = pd;
  }
  // V half: thread -> (dg = tid>>4 : 4 d's, g = tid&15 : 4 consecutive s).
  // col' base for s-group g: cp = ((g>>3)&1)*32 + (g&3)*8 + ((g>>2)&1)*4.
  {
    const int g = tid & 15, dg = tid >> 4;
    const int cp = ((g >> 3) & 1) * 32 + (g & 3) * 8 + ((g >> 2) & 1) * 4;
    const float* vb = qg + (size_t)(128 + dg * 4) * 1024 + s0 + g * 4;
#pragma unroll
    for (int i = 0; i < 4; ++i) {
      f32x4 v = *(const f32x4*)(vb + (size_t)i * 1024);
      const int d = dg * 4 + i;
      *(uint2*)&img[4096 + d * 64 + (cp ^ ((d & 7) << 3))] =
          make_uint2(pkbf(v.x, v.y), pkbf(v.z, v.w));
    }
  }
  __syncthreads();
  if (tid < 64) {
    f32x4 p4 = *(const f32x4*)&part[tid * 4];
    wtab[(size_t)B * 64 + tid] = fexp2(QSCALE * ((p4.x + p4.y) + (p4.z + p4.w)));
  }
}

// ---- kernel 2: 1-qcol flash attention, factorized class stream -------------
__global__ __launch_bounds__(256, 4)
void attn_kernel(const float* __restrict__ qkv, const int* __restrict__ seg,
                 const float* __restrict__ tok, const u16* __restrict__ tiles,
                 const float* __restrict__ wtab, float* __restrict__ out) {
  // [buf0 16KB | buf1 16KB] = 32768 B -> 4+ blocks/CU; epilogue fbuf
  // 64x68 f32 = 17408 B reuses the tile region.
  __shared__ __align__(16) u16 smem[16384];

  const int L  = blockIdx.x;                     // 0..1023
  const int bh = (L & 7) * 8 + ((L >> 3) & 7);   // same batch -> same XCD
  const int qt = L >> 6;                          // 0..15 (64-query block)
  const int b  = bh >> 3;
  const int tid = threadIdx.x, wave = tid >> 6, lane = tid & 63;
  const int quad = lane >> 4, l16 = lane & 15;

  const float* qg   = qkv + (size_t)bh * 192 * 1024;
  const int*   segb = seg + b * 1024;
  const u16*   tbh  = tiles + (size_t)bh * (16 * 8192);
  const float* wbh  = wtab + (size_t)bh * (16 * 64);

  // --- per-lane query info: lane owns query l16 of this wave's 16 ----------
  const int tq = qt * 64 + wave * 16 + l16;
  const int myc = segb[tq];
  int sq[4];                           // classes of epilogue rows
#pragma unroll
  for (int r = 0; r < 4; ++r) sq[r] = segb[qt * 64 + wave * 16 + quad * 4 + r];

  // --- Q fragments, null stream only (B-layout: n=l16=query, k=d) ----------
  const float* tn = tok + 8 * 192;
  union { u32 w[4]; bf16x8 v; } q0[2];
#pragma unroll
  for (int kc = 0; kc < 2; ++kc)
#pragma unroll
    for (int jj = 0; jj < 4; ++jj) {
      int d = kc * 32 + quad * 8 + jj * 2;
      float a0 = qg[(size_t)d * 1024 + tq];
      float a1 = qg[(size_t)(d + 1) * 1024 + tq];
      q0[kc].w[jj] = pkbf((a0 + tn[d]) * QSCALE, (a1 + tn[d + 1]) * QSCALE);
    }

  f32x4 O0[4], Ob[4];
#pragma unroll
  for (int dt = 0; dt < 4; ++dt) {
    O0[dt] = (f32x4){0.f, 0.f, 0.f, 0.f};
    Ob[dt] = (f32x4){0.f, 0.f, 0.f, 0.f};
  }
  float rs0 = 0.f, rsb = 0.f;

  // prologue: DMA tile 0 into buf0
  {
    const char* src = (const char*)tbh + tid * 16;
    char* dst = (char*)smem + tid * 16;
#pragma unroll
    for (int i = 0; i < 4; ++i) gload_lds16(src + i * 4096, dst + i * 4096);
  }

  const int xq = (l16 & 7) << 3;   // XOR for all row&7 == l16&7 accesses

  // ---- key-tile loop (16 x 64 keys) ----------------------------------------
#pragma unroll 2
  for (int kt = 0; kt < 16; ++kt) {
    const int s0 = kt * 64;
    __syncthreads();            // drains our DMA (vmcnt 0) + frees other buf
    if (kt + 1 < 16) {          // prefetch next tile across the whole compute
      const char* src = (const char*)tbh + (size_t)(kt + 1) * 16384 + tid * 16;
      char* dst = (char*)smem + ((kt + 1) & 1) * 16384 + tid * 16;
#pragma unroll
      for (int i = 0; i < 4; ++i) gload_lds16(src + i * 4096, dst + i * 4096);
    }
    // masked per-key class factors, TRANSIENT (dead after softmax).  Loads
    // issue here; L2 latency covered by the QK MFMA cluster below.
    f32x4 wm[4];
#pragma unroll
    for (int n4 = 0; n4 < 4; ++n4) {
      const int4  s4 = *(const int4*)&segb[s0 + n4 * 16 + quad * 4];
      const f32x4 wv = *(const f32x4*)&wbh[s0 + n4 * 16 + quad * 4];
      wm[n4][0] = (s4.x == myc) ? wv[0] : 0.f;
      wm[n4][1] = (s4.y == myc) ? wv[1] : 0.f;
      wm[n4][2] = (s4.z == myc) ? wv[2] : 0.f;
      wm[n4][3] = (s4.w == myc) ? wv[3] : 0.f;
    }

    const u16* ktr = smem + (kt & 1) * 8192;   // K image [s][64]
    const u16* vls = ktr + 4096;               // V image [d][64]

    // ---- S^T = K Q^T, null stream only ------------------------------------
    f32x4 S[4];
#pragma unroll
    for (int n4 = 0; n4 < 4; ++n4) {
      const int srow = n4 * 16 + l16;          // srow&7 == l16&7 -> xq
      f32x4 a0 = {0.f, 0.f, 0.f, 0.f};
#pragma unroll
      for (int kc = 0; kc < 2; ++kc) {
        bf16x8 kfr = *(const bf16x8*)&ktr[srow * 64 + ((kc * 32 + quad * 8) ^ xq)];
        a0 = __builtin_amdgcn_mfma_f32_16x16x32_bf16(kfr, q0[kc].v, a0, 0, 0, 0);
      }
      S[n4] = a0;
    }

    // ---- softmax: p0 = exp2(S); pb = p0 * wm ------------------------------
    float p0[4][4], pb[4][4];
#pragma unroll
    for (int n4 = 0; n4 < 4; ++n4)
#pragma unroll
      for (int r = 0; r < 4; ++r) {
        p0[n4][r] = fexp2(S[n4][r]);
        pb[n4][r] = p0[n4][r] * wm[n4][r];
      }
#pragma unroll
    for (int n4 = 0; n4 < 4; ++n4) {
      rs0 += (p0[n4][0] + p0[n4][1]) + (p0[n4][2] + p0[n4][3]);
      rsb += (pb[n4][0] + pb[n4][1]) + (pb[n4][2] + pb[n4][3]);
    }
    // pack A-frags: elem j of pa[kc] is key col' = kc*32+quad*8+j,
    // i.e. (n4 = 2kc + (j>>2), r = j&3) -- static, no cross-lane.
    union { u32 w[4]; bf16x8 v; } pa0[2], pab[2];
#pragma unroll
    for (int kc = 0; kc < 2; ++kc) {
      pa0[kc].w[0] = pkbf(p0[2 * kc][0],     p0[2 * kc][1]);
      pa0[kc].w[1] = pkbf(p0[2 * kc][2],     p0[2 * kc][3]);
      pa0[kc].w[2] = pkbf(p0[2 * kc + 1][0], p0[2 * kc + 1][1]);
      pa0[kc].w[3] = pkbf(p0[2 * kc + 1][2], p0[2 * kc + 1][3]);
      pab[kc].w[0] = pkbf(pb[2 * kc][0],     pb[2 * kc][1]);
      pab[kc].w[1] = pkbf(pb[2 * kc][2],     pb[2 * kc][3]);
      pab[kc].w[2] = pkbf(pb[2 * kc + 1][0], pb[2 * kc + 1][1]);
      pab[kc].w[3] = pkbf(pb[2 * kc + 1][2], pb[2 * kc + 1][3]);
    }

    // ---- O += P V ---------------------------------------------------------
#pragma unroll
    for (int kc = 0; kc < 2; ++kc) {
      const int co = (kc * 32 + quad * 8) ^ xq;
#pragma unroll
      for (int dt = 0; dt < 4; ++dt) {
        bf16x8 vfr = *(const bf16x8*)&vls[(dt * 16 + l16) * 64 + co];
        O0[dt] = __builtin_amdgcn_mfma_f32_16x16x32_bf16(pa0[kc].v, vfr, O0[dt], 0, 0, 0);
        Ob[dt] = __builtin_amdgcn_mfma_f32_16x16x32_bf16(pab[kc].v, vfr, Ob[dt], 0, 0, 0);
      }
    }
  }

  // ---- denominators: reduce across quads, then broadcast rows --------------
  rs0 += __shfl_xor(rs0, 16, 64);  rs0 += __shfl_xor(rs0, 32, 64);
  rsb += __shfl_xor(rsb, 16, 64);  rsb += __shfl_xor(rsb, 32, 64);
  float inv0[4], invb[4];
#pragma unroll
  for (int r = 0; r < 4; ++r) {
    float d0 = __shfl(rs0, quad * 4 + r, 16);   // denom of query quad*4+r
    float db = __shfl(rsb, quad * 4 + r, 16);
    inv0[r] = (d0 > 0.f) ? 1.f / d0 : 0.f;
    invb[r] = (db > 0.f) ? 1.f / db : 0.f;
  }

  // ---- epilogue: divide, add analytic v-biases, transpose via LDS, store ---
  __syncthreads();                        // all LDS tile reads done
  float* fbuf = (float*)smem;             // [64 d][68] fp32 (17408 B)
  const float* tvn = tok + 8 * 192 + 128;
#pragma unroll
  for (int dt = 0; dt < 4; ++dt) {
    const int d = dt * 16 + l16;
    const float bn = tvn[d];
    f32x4 wv;
#pragma unroll
    for (int r = 0; r < 4; ++r) {
      float bc = tok[sq[r] * 192 + 128 + d];
      wv[r] = 0.5f * (O0[dt][r] * inv0[r] + bn + Ob[dt][r] * invb[r] + bc);
    }
    *(f32x4*)&fbuf[d * 68 + wave * 16 + quad * 4] = wv;
  }
  __syncthreads();
  {
    // out flat = d*65536 + bh*1024 + t   (stacked (ch, bH, T) row-major)
    const size_t obase = (size_t)bh * 1024 + qt * 64;
    for (int i = tid; i < 4096; i += 256) {
      int d = i >> 6, t = i & 63;
      out[(size_t)d * 65536 + obase + t] = fbuf[d * 68 + t];
    }
  }
}

// ---- host ------------------------------------------------------------------
extern "C" void kernel_launch(void* const* d_in, const int* in_sizes, int n_in,
                              void* d_out, int out_size, void* d_ws, size_t ws_size,
                              hipStream_t stream) {
  (void)in_sizes; (void)n_in; (void)out_size; (void)ws_size;
  const float* qkv   = (const float*)d_in[0];
  const int*   amask = (const int*)d_in[1];
  const float* emb   = (const float*)d_in[2];
  const float* wcls  = (const float*)d_in[3];
  float* tok   = (float*)d_ws;                       // 1728 floats
  u16*   tiles = (u16*)((char*)d_ws + 8192);         // 16 MiB of tile images
  float* wtab  = (float*)((char*)d_ws + 8192 + 16 * 1024 * 1024);  // 256 KiB
  float* out = (float*)d_out;

  hipLaunchKernelGGL(tok_kernel, dim3(432), dim3(256), 0, stream, wcls, emb, tok);
  hipLaunchKernelGGL(prep_kernel, dim3(1024), dim3(256), 0, stream,
                     qkv, amask, tok, tiles, wtab);
  hipLaunchKernelGGL(attn_kernel, dim3(1024), dim3(256), 0, stream,
                     qkv, amask, tok, tiles, wtab, out);
}